// Round 6
// baseline (2148.456 us; speedup 1.0000x reference)
//
#include <hip/hip_runtime.h>
#include <hip/hip_bf16.h>
#include <stdint.h>

// TiedEmbeddingLinear: out[8192, 32768] = x[8192,4096] . W^T
// Pass 1: dequant NF4 W -> bf16 (ws). Pass 2: x fp32 -> bf16 (ws).
// Pass 3: 256x256 4-phase-per-K-tile bf16 NT-GEMM, asm ds_read_b128 +
// counted tail-aware vmcnt (R5). R6: 32x32x16 MFMA (−17% matrix cycles,
// 2382 vs 2075 TF ceiling; full-128B-line stores) + revert NT stores
// (R5 showed +0.35GB HBM write amplification).

#define M_DIM 8192
#define N_DIM 32768
#define K_DIM 4096
#define NT    64        // K / BK, BK = 64

typedef __attribute__((ext_vector_type(8))) short short8;
typedef __attribute__((ext_vector_type(4))) float f32x4;
typedef __attribute__((ext_vector_type(16))) float f32x16;

__device__ __forceinline__ ushort f2bf(float f) {
    union { __hip_bfloat16 b; ushort u; } cv;
    cv.b = __float2bfloat16(f);
    return cv.u;
}

__device__ __forceinline__ void gload16(const ushort* g, ushort* l) {
    __builtin_amdgcn_global_load_lds(
        (const __attribute__((address_space(1))) unsigned int*)g,
        (__attribute__((address_space(3))) unsigned int*)l,
        16, 0, 0);
}

// inline-asm LDS read: opaque to alias analysis -> no compiler vmcnt drains.
__device__ __forceinline__ short8 ldsread128(const ushort* p) {
    short8 r;
    uint32_t a = (uint32_t)(uintptr_t)(const __attribute__((address_space(3))) ushort*)p;
    asm volatile("ds_read_b128 %0, %1" : "=v"(r) : "v"(a));
    return r;
}

#define BAR()    asm volatile("s_barrier" ::: "memory")
#define VMCNT4() asm volatile("s_waitcnt vmcnt(4)" ::: "memory")
#define VMCNT0() asm volatile("s_waitcnt vmcnt(0)" ::: "memory")
#define LGKM0()  do { asm volatile("s_waitcnt lgkmcnt(0)" ::: "memory"); \
                      __builtin_amdgcn_sched_barrier(0); } while (0)

// ---------------- pass 1: dequant W ----------------
__global__ __launch_bounds__(256) void dequant_w(
    const int* __restrict__ qw, const float* __restrict__ cb,
    uint32_t* __restrict__ wout)
{
    __shared__ uint32_t lut[256];
    const int tid = threadIdx.x;
    {
        const uint32_t h = f2bf(cb[(tid >> 4) & 15]);   // high nibble -> even d
        const uint32_t l = f2bf(cb[tid & 15]);          // low nibble  -> odd d
        lut[tid] = h | (l << 16);
    }
    __syncthreads();

    const size_t base = (size_t)blockIdx.x * 256 + tid;
    const int4* q4 = (const int4*)qw;
    uint4* w4 = (uint4*)wout;
    #pragma unroll
    for (int it = 0; it < 16; ++it) {
        const size_t idx = base + (size_t)it * (4096 * 256);
        const int4 q = q4[idx];
        uint4 w;
        w.x = lut[q.x & 255]; w.y = lut[q.y & 255];
        w.z = lut[q.z & 255]; w.w = lut[q.w & 255];
        w4[idx] = w;
    }
}

// ---------------- pass 2: x fp32 -> bf16 ----------------
__global__ __launch_bounds__(256) void conv_x(
    const float* __restrict__ x, ushort* __restrict__ xb)
{
    const size_t base = (size_t)blockIdx.x * 256 + threadIdx.x;
    #pragma unroll
    for (int it = 0; it < 8; ++it) {
        const size_t idx = (base + (size_t)it * (2048 * 256)) * 8;
        const float4 a = *(const float4*)(x + idx);
        const float4 b = *(const float4*)(x + idx + 4);
        short8 o;
        o[0] = f2bf(a.x); o[1] = f2bf(a.y); o[2] = f2bf(a.z); o[3] = f2bf(a.w);
        o[4] = f2bf(b.x); o[5] = f2bf(b.y); o[6] = f2bf(b.z); o[7] = f2bf(b.w);
        *(short8*)(xb + idx) = o;
    }
}

// ---------------- pass 3: 256^2 bf16 NT-GEMM, 32x32x16 MFMA ----------------
__global__ __launch_bounds__(512, 2) void gemm_8ph(
    const ushort* __restrict__ xb, const ushort* __restrict__ wb,
    const float* __restrict__ absmax, float* __restrict__ out)
{
    __shared__ ushort smA[32768];   // 64 KiB: (buf*2+half)*8192
    __shared__ ushort smB[32768];   // 64 KiB

    const int tid  = threadIdx.x;
    const int lane = tid & 63;
    const int wv   = tid >> 6;      // 0..7
    const int wm   = wv >> 2;       // 0..1  (A half / 128-row block)
    const int wn   = wv & 3;        // 0..3  (64-col block)

    const int bid = blockIdx.x;
    const int gm0 = (bid & 31) << 8;    // 32 m-tiles fast: B panels shared, A L3-resident
    const int gn0 = (bid >> 5) << 8;

    const int l8    = lane >> 3;             // row within 8-row staging chunk
    const int sgran = (lane & 7) ^ l8;       // swizzled SOURCE granule (16B units)

    const ushort* aSrc = xb + (size_t)(gm0 + wv * 16 + l8) * K_DIM + sgran * 8;
    const ushort* bSrc = wb + (size_t)(gn0 + wv * 16 + l8) * K_DIM + sgran * 8;

    // 32x32x16 fragment decomposition
    const int l31 = lane & 31;      // operand row (A m-row / B n-row)
    const int g2  = lane >> 5;      // k-granule half (k = g2*8 + e)
    const int lr7 = lane & 7;       // swizzle key == row&7 (ROW multiple of 32)
    const int brow0 = (wn & 1) * 64;

    f32x16 acc[4][2] = {};
    short8 af[4], bf[2][4];

    // swizzled fragment read: granule (s*2+g2) XOR (row&7)
    #define LDFRAG32(P, ROW, S) \
        ldsread128((P) + ((ROW) + l31) * 64 + ((((S) * 2 + g2) ^ lr7) * 8))

    #define STAGE_A(TB, H, KT) do { \
        ushort* _d = smA + ((TB) * 2 + (H)) * 8192 + wv * 1024; \
        gload16(aSrc + (size_t)((H) * 128 + 0) * K_DIM + (KT) * 64, _d); \
        gload16(aSrc + (size_t)((H) * 128 + 8) * K_DIM + (KT) * 64, _d + 512); \
    } while (0)
    #define STAGE_B(TB, H, KT) do { \
        ushort* _d = smB + ((TB) * 2 + (H)) * 8192 + wv * 1024; \
        gload16(bSrc + (size_t)((H) * 128 + 0) * K_DIM + (KT) * 64, _d); \
        gload16(bSrc + (size_t)((H) * 128 + 8) * K_DIM + (KT) * 64, _d + 512); \
    } while (0)

    // one m-tile x (2 n-tiles x 4 k-slices) = 8 MFMA; s outer, n inner
    // (alternating accumulators -> chain distance 2 covers MFMA latency)
    #define MFMAS32(MI) do { \
        __builtin_amdgcn_s_setprio(1); \
        _Pragma("unroll") \
        for (int s = 0; s < 4; ++s) \
            _Pragma("unroll") \
            for (int n = 0; n < 2; ++n) \
                acc[MI][n] = __builtin_amdgcn_mfma_f32_32x32x16_bf16( \
                    af[s], bf[n][s], acc[MI][n], 0, 0, 0); \
        __builtin_amdgcn_s_setprio(0); \
    } while (0)

    // ---- prologue: A(0),B(0) -> buf0; B(1) -> buf1 ----
    STAGE_A(0, 0, 0); STAGE_A(0, 1, 0);
    STAGE_B(0, 0, 0); STAGE_B(0, 1, 0);
    STAGE_B(1, 0, 1); STAGE_B(1, 1, 1);
    VMCNT4();           // A(0),B(0) landed; B(1)'s 4 loads stay in flight
    BAR();

    for (int j = 0; j < NT; ++j) {
        const int buf = j & 1;
        const ushort* Ar = smA + (buf * 2 + wm) * 8192;
        const ushort* Br = smB + (buf * 2 + (wn >> 1)) * 8192;

        // ---- P1: read all B (2n x 4s) + A m0; stage A-half0(j+1) -> buf^1 ----
        #pragma unroll
        for (int s = 0; s < 4; ++s) {
            bf[0][s] = LDFRAG32(Br, brow0 + 0,  s);
            bf[1][s] = LDFRAG32(Br, brow0 + 32, s);
        }
        #pragma unroll
        for (int s = 0; s < 4; ++s)
            af[s] = LDFRAG32(Ar, 0 * 32, s);
        if (j + 1 < NT) STAGE_A(buf ^ 1, 0, j + 1);
        BAR();
        LGKM0();
        MFMAS32(0);
        BAR();

        // ---- P2: read A m1; stage A-half1(j+1) ----
        #pragma unroll
        for (int s = 0; s < 4; ++s)
            af[s] = LDFRAG32(Ar, 1 * 32, s);
        if (j + 1 < NT) STAGE_A(buf ^ 1, 1, j + 1);
        BAR();
        LGKM0();
        MFMAS32(1);
        BAR();

        // ---- P3: read A m2; stage B-half0(j+2) -> buf (B(j) fully read in P1) ----
        #pragma unroll
        for (int s = 0; s < 4; ++s)
            af[s] = LDFRAG32(Ar, 2 * 32, s);
        if (j + 2 < NT) STAGE_B(buf, 0, j + 2);
        BAR();
        LGKM0();
        MFMAS32(2);
        BAR();

        // ---- P4: read A m3; stage B-half1(j+2); tail-aware counted vmcnt ----
        #pragma unroll
        for (int s = 0; s < 4; ++s)
            af[s] = LDFRAG32(Ar, 3 * 32, s);
        if (j + 2 < NT) STAGE_B(buf, 1, j + 2);
        BAR();
        LGKM0();
        MFMAS32(3);
        if (j + 2 < NT) {
            VMCNT4();   // leave B(j+2)'s 4 loads in flight; A(j+1),B(j+1) retired
        } else {
            VMCNT0();   // tail: nothing newer in flight -> drain so A(j+1) lands
        }
        BAR();
    }

    // ---- epilogue: absmax[col] scale, plain fp32 stores (full 128B lines) ----
    float am[2];
    #pragma unroll
    for (int n = 0; n < 2; ++n)
        am[n] = absmax[gn0 + wn * 64 + n * 32 + l31];

    const int row0 = gm0 + wm * 128 + 4 * g2;   // + (reg&3) + 8*(reg>>2)
    const int col0 = gn0 + wn * 64 + l31;
    #pragma unroll
    for (int mi = 0; mi < 4; ++mi) {
        #pragma unroll
        for (int ni = 0; ni < 2; ++ni) {
            #pragma unroll
            for (int r = 0; r < 16; ++r) {
                const int row = row0 + mi * 32 + (r & 3) + 8 * (r >> 2);
                out[(size_t)row * N_DIM + col0 + ni * 32] = acc[mi][ni][r] * am[ni];
            }
        }
    }
}

extern "C" void kernel_launch(void* const* d_in, const int* in_sizes, int n_in,
                              void* d_out, int out_size, void* d_ws, size_t ws_size,
                              hipStream_t stream) {
    const float* x      = (const float*)d_in[0];
    const int*   qw     = (const int*)d_in[1];
    const float* absmax = (const float*)d_in[2];
    const float* cb     = (const float*)d_in[3];
    float* out = (float*)d_out;

    const size_t W_BYTES = (size_t)N_DIM * K_DIM * 2;   // 256 MiB bf16 W
    uint32_t* wq  = (uint32_t*)d_ws;
    ushort*   xbf = (ushort*)((char*)d_ws + W_BYTES);

    dequant_w<<<4096, 256, 0, stream>>>(qw, cb, wq);
    conv_x<<<2048, 256, 0, stream>>>(x, xbf);
    gemm_8ph<<<dim3((M_DIM / 256) * (N_DIM / 256)), dim3(512), 0, stream>>>(
        xbf, (const ushort*)wq, absmax, out);
}

// Round 8
// 1935.119 us; speedup vs baseline: 1.1102x; 1.1102x over previous
//
#include <hip/hip_runtime.h>
#include <hip/hip_bf16.h>
#include <stdint.h>

// TiedEmbeddingLinear: out[8192, 32768] = x[8192,4096] . W^T
// Pass 1: dequant NF4 W -> bf16 (ws). Pass 2: x fp32 -> bf16 (ws).
// Pass 3: 256x256 bf16 NT-GEMM, 16x16x32 MFMA, asm ds_read_b128 + counted
// tail-aware vmcnt (R5 base). R8: LEGAL read-hoist — all Q1/Q2 reads issued
// at P1-top (earliest point after the staging-retirement barrier), Q2 runs
// with no LDS wait; af m4-7 prefetched post-Q2. RULE (R7 NaN post-mortem):
// vmcnt is per-wave; reads of cooperatively-staged LDS must NOT cross the
// barrier that follows all waves' vmcnt retirement.

#define M_DIM 8192
#define N_DIM 32768
#define K_DIM 4096
#define NT    64        // K / BK, BK = 64

typedef __attribute__((ext_vector_type(8))) short short8;
typedef __attribute__((ext_vector_type(4))) float f32x4;

__device__ __forceinline__ ushort f2bf(float f) {
    union { __hip_bfloat16 b; ushort u; } cv;
    cv.b = __float2bfloat16(f);
    return cv.u;
}

__device__ __forceinline__ void gload16(const ushort* g, ushort* l) {
    __builtin_amdgcn_global_load_lds(
        (const __attribute__((address_space(1))) unsigned int*)g,
        (__attribute__((address_space(3))) unsigned int*)l,
        16, 0, 0);
}

// inline-asm LDS read: opaque to alias analysis -> no compiler vmcnt drains.
__device__ __forceinline__ short8 ldsread128(const ushort* p) {
    short8 r;
    uint32_t a = (uint32_t)(uintptr_t)(const __attribute__((address_space(3))) ushort*)p;
    asm volatile("ds_read_b128 %0, %1" : "=v"(r) : "v"(a));
    return r;
}

#define BAR()    asm volatile("s_barrier" ::: "memory")
#define VMCNT4() asm volatile("s_waitcnt vmcnt(4)" ::: "memory")
#define VMCNT0() asm volatile("s_waitcnt vmcnt(0)" ::: "memory")
#define LGKM0()  do { asm volatile("s_waitcnt lgkmcnt(0)" ::: "memory"); \
                      __builtin_amdgcn_sched_barrier(0); } while (0)
#define SCHED0() __builtin_amdgcn_sched_barrier(0)

// ---------------- pass 1: dequant W ----------------
__global__ __launch_bounds__(256) void dequant_w(
    const int* __restrict__ qw, const float* __restrict__ cb,
    uint32_t* __restrict__ wout)
{
    __shared__ uint32_t lut[256];
    const int tid = threadIdx.x;
    {
        const uint32_t h = f2bf(cb[(tid >> 4) & 15]);   // high nibble -> even d
        const uint32_t l = f2bf(cb[tid & 15]);          // low nibble  -> odd d
        lut[tid] = h | (l << 16);
    }
    __syncthreads();

    const size_t base = (size_t)blockIdx.x * 256 + tid;
    const int4* q4 = (const int4*)qw;
    uint4* w4 = (uint4*)wout;
    #pragma unroll
    for (int it = 0; it < 16; ++it) {
        const size_t idx = base + (size_t)it * (4096 * 256);
        const int4 q = q4[idx];
        uint4 w;
        w.x = lut[q.x & 255]; w.y = lut[q.y & 255];
        w.z = lut[q.z & 255]; w.w = lut[q.w & 255];
        w4[idx] = w;
    }
}

// ---------------- pass 2: x fp32 -> bf16 ----------------
__global__ __launch_bounds__(256) void conv_x(
    const float* __restrict__ x, ushort* __restrict__ xb)
{
    const size_t base = (size_t)blockIdx.x * 256 + threadIdx.x;
    #pragma unroll
    for (int it = 0; it < 8; ++it) {
        const size_t idx = (base + (size_t)it * (2048 * 256)) * 8;
        const float4 a = *(const float4*)(x + idx);
        const float4 b = *(const float4*)(x + idx + 4);
        short8 o;
        o[0] = f2bf(a.x); o[1] = f2bf(a.y); o[2] = f2bf(a.z); o[3] = f2bf(a.w);
        o[4] = f2bf(b.x); o[5] = f2bf(b.y); o[6] = f2bf(b.z); o[7] = f2bf(b.w);
        *(short8*)(xb + idx) = o;
    }
}

// ---------------- pass 3: 256^2 bf16 NT-GEMM, legal read-hoist ----------
__global__ __launch_bounds__(512, 2) void gemm_8ph(
    const ushort* __restrict__ xb, const ushort* __restrict__ wb,
    const float* __restrict__ absmax, float* __restrict__ out)
{
    __shared__ ushort smA[32768];   // 64 KiB: (buf*2+half)*8192
    __shared__ ushort smB[32768];   // 64 KiB

    const int tid  = threadIdx.x;
    const int lane = tid & 63;
    const int wv   = tid >> 6;      // 0..7
    const int wm   = wv >> 2;       // 0..1
    const int wn   = wv & 3;        // 0..3

    const int bid = blockIdx.x;
    const int gm0 = (bid & 31) << 8;    // 32 m-tiles fast: B panels shared, A L3-resident
    const int gn0 = (bid >> 5) << 8;

    const int l8    = lane >> 3;             // row within 8-row staging chunk
    const int sgran = (lane & 7) ^ l8;       // swizzled SOURCE granule (16B units)

    const ushort* aSrc = xb + (size_t)(gm0 + wv * 16 + l8) * K_DIM + sgran * 8;
    const ushort* bSrc = wb + (size_t)(gn0 + wv * 16 + l8) * K_DIM + sgran * 8;

    const int lr  = lane & 15;
    const int g   = lane >> 4;
    const int lr7 = lane & 7;
    const int brow0 = (wn & 1) * 64;

    f32x4  acc[8][4] = {};
    short8 af[4][2], bf[4][2];

    #define LDFRAG(P, ROW, S) \
        ldsread128((P) + ((ROW) + lr) * 64 + ((((S) * 4 + g) ^ lr7) * 8))

    #define STAGE_A(TB, H, KT) do { \
        ushort* _d = smA + ((TB) * 2 + (H)) * 8192 + wv * 1024; \
        gload16(aSrc + (size_t)((H) * 128 + 0) * K_DIM + (KT) * 64, _d); \
        gload16(aSrc + (size_t)((H) * 128 + 8) * K_DIM + (KT) * 64, _d + 512); \
    } while (0)
    #define STAGE_B(TB, H, KT) do { \
        ushort* _d = smB + ((TB) * 2 + (H)) * 8192 + wv * 1024; \
        gload16(bSrc + (size_t)((H) * 128 + 0) * K_DIM + (KT) * 64, _d); \
        gload16(bSrc + (size_t)((H) * 128 + 8) * K_DIM + (KT) * 64, _d + 512); \
    } while (0)

    #define MFMAS(MB, NB) do { \
        __builtin_amdgcn_s_setprio(1); \
        _Pragma("unroll") \
        for (int m = 0; m < 4; ++m) \
            _Pragma("unroll") \
            for (int n = 0; n < 2; ++n) \
                _Pragma("unroll") \
                for (int s = 0; s < 2; ++s) \
                    acc[(MB) + m][(NB) + n] = __builtin_amdgcn_mfma_f32_16x16x32_bf16( \
                        af[m][s], bf[(NB) + n][s], acc[(MB) + m][(NB) + n], 0, 0, 0); \
        __builtin_amdgcn_s_setprio(0); \
    } while (0)

    // ---- prologue: A(0),B(0) -> buf0; B(1) -> buf1 ----
    STAGE_A(0, 0, 0); STAGE_A(0, 1, 0);
    STAGE_B(0, 0, 0); STAGE_B(0, 1, 0);
    STAGE_B(1, 0, 1); STAGE_B(1, 1, 1);
    VMCNT4();           // A(0),B(0) landed; B(1)'s 4 loads stay in flight
    BAR();              // <- all waves' A(0),B(0) staging retired before any read

    for (int j = 0; j < NT; ++j) {
        const int buf = j & 1;
        const ushort* Ar = smA + (buf * 2 + wm) * 8192;
        const ushort* Br = smB + (buf * 2 + (wn >> 1)) * 8192;

        // ---- P1: issue ALL Q1/Q2 reads (legal: tile-j staging retired by
        //      the barrier just crossed); stage A-half0(j+1); Q1 MFMA ----
        #pragma unroll
        for (int m = 0; m < 4; ++m) {
            af[m][0] = LDFRAG(Ar, m * 16, 0);
            af[m][1] = LDFRAG(Ar, m * 16, 1);
        }
        #pragma unroll
        for (int n = 0; n < 4; ++n) {
            bf[n][0] = LDFRAG(Br, brow0 + n * 16, 0);
            bf[n][1] = LDFRAG(Br, brow0 + n * 16, 1);
        }
        if (j + 1 < NT) STAGE_A(buf ^ 1, 0, j + 1);
        BAR();
        LGKM0();            // all 16 reads resident
        MFMAS(0, 0);
        BAR();

        // ---- P2: Q2 — operands already in regs, NO LDS wait;
        //      post-MFMA: prefetch af <- A(j) m4-7 (intra-wave, legal) ----
        if (j + 1 < NT) STAGE_A(buf ^ 1, 1, j + 1);
        BAR();
        MFMAS(0, 2);
        SCHED0();
        #pragma unroll
        for (int m = 0; m < 4; ++m) {
            af[m][0] = LDFRAG(Ar, (4 + m) * 16, 0);
            af[m][1] = LDFRAG(Ar, (4 + m) * 16, 1);
        }
        BAR();

        // ---- P3: Q3; stage B-half0(j+2) -> buf (B(j) reads all done P1) ----
        if (j + 2 < NT) STAGE_B(buf, 0, j + 2);
        BAR();
        LGKM0();            // af m4-7 resident (hid under BAR+stage+BAR+Q2)
        MFMAS(4, 2);
        BAR();

        // ---- P4: Q4 all-in-regs; stage B-half1(j+2); tail-aware vmcnt ----
        if (j + 2 < NT) STAGE_B(buf, 1, j + 2);
        BAR();
        MFMAS(4, 0);
        if (j + 2 < NT) {
            VMCNT4();   // retire A(j+1),B(j+1); leave B(j+2)'s 4 in flight
        } else {
            VMCNT0();   // tail: no B(j+2) in flight -> drain (R4 lesson)
        }
        BAR();          // <- staging-retirement barrier: next P1 reads are legal
    }

    // ---- epilogue: absmax[col] scale, plain fp32 stores ----
    float am[4];
    #pragma unroll
    for (int n = 0; n < 4; ++n)
        am[n] = absmax[gn0 + wn * 64 + n * 16 + lr];

    const int row0 = gm0 + wm * 128 + g * 4;
    const int col0 = gn0 + wn * 64 + lr;
    #pragma unroll
    for (int m = 0; m < 8; ++m) {
        #pragma unroll
        for (int n = 0; n < 4; ++n) {
            #pragma unroll
            for (int r = 0; r < 4; ++r) {
                out[(size_t)(row0 + m * 16 + r) * N_DIM + col0 + n * 16] =
                    acc[m][n][r] * am[n];
            }
        }
    }
}

extern "C" void kernel_launch(void* const* d_in, const int* in_sizes, int n_in,
                              void* d_out, int out_size, void* d_ws, size_t ws_size,
                              hipStream_t stream) {
    const float* x      = (const float*)d_in[0];
    const int*   qw     = (const int*)d_in[1];
    const float* absmax = (const float*)d_in[2];
    const float* cb     = (const float*)d_in[3];
    float* out = (float*)d_out;

    const size_t W_BYTES = (size_t)N_DIM * K_DIM * 2;   // 256 MiB bf16 W
    uint32_t* wq  = (uint32_t*)d_ws;
    ushort*   xbf = (ushort*)((char*)d_ws + W_BYTES);

    dequant_w<<<4096, 256, 0, stream>>>(qw, cb, wq);
    conv_x<<<2048, 256, 0, stream>>>(x, xbf);
    gemm_8ph<<<dim3((M_DIM / 256) * (N_DIM / 256)), dim3(512), 0, stream>>>(
        xbf, (const ushort*)wq, absmax, out);
}